// Round 1
// baseline (729.666 us; speedup 1.0000x reference)
//
#include <hip/hip_runtime.h>
#include <hip/hip_bf16.h>

#define NB    8192
#define DICT  14
#define SE    32
#define CC    64
#define EDIM  256
#define NZV   512
#define C1N   16
#define C2N   32
#define J400  400    // 16*25 (phi conv1 output, flattened o*25+pix)
#define K800  800    // 32*25 (phi conv2 output, flattened o*25+pix)

// ---------------- prep: normalize embedding rows (max_norm=1 semantics) ----
__global__ __launch_bounds__(64) void k_norm_embed(const float* __restrict__ tab,
                                                   float* __restrict__ tn) {
    int d = blockIdx.x, l = threadIdx.x;
    float v = (l < SE) ? tab[d * SE + l] : 0.f;
    float s = v * v;
    #pragma unroll
    for (int o = 32; o > 0; o >>= 1) s += __shfl_down(s, o, 64);
    s = __shfl(s, 0, 64);
    float sc = fminf(1.f, 1.f / (sqrtf(s) + 1e-7f));
    if (l < SE) tn[d * SE + l] = v * sc;
}

// ---------------- prep: L2-normalize z_vectors (eps=0) ---------------------
__global__ __launch_bounds__(256) void k_norm_z(const float* __restrict__ z,
                                                float* __restrict__ zn) {
    __shared__ float red[4];
    int r = blockIdx.x, t = threadIdx.x;
    float v = z[r * EDIM + t];
    float s = v * v;
    #pragma unroll
    for (int o = 32; o > 0; o >>= 1) s += __shfl_down(s, o, 64);
    if ((t & 63) == 0) red[t >> 6] = s;
    __syncthreads();
    float tot = red[0] + red[1] + red[2] + red[3];
    zn[r * EDIM + t] = v / sqrtf(tot);
}

// ---- A[d][c1][f] = sum_c0 We[c1,c0,f] * tn[d,c0]   (f = ky*3+kx) ----------
__global__ __launch_bounds__(256) void k_build_A(const float* __restrict__ we,
                                                 const float* __restrict__ tn,
                                                 float* __restrict__ A) {
    int i = blockIdx.x * 256 + threadIdx.x;
    if (i >= DICT * CC * 9) return;
    int f = i % 9, c1 = (i / 9) % CC, d = i / (9 * CC);
    float acc = 0.f;
    #pragma unroll
    for (int c0 = 0; c0 < SE; c0++) acc += we[(c1 * SE + c0) * 9 + f] * tn[d * SE + c0];
    A[i] = acc;
}

// ---- beff[t][j=(o,y,x)]: phi-conv1 effective bias.
// phi1 input = xs (includes embed bias be); phi2 input = xsp - xs (be cancels).
__global__ __launch_bounds__(256) void k_build_beff(const float* __restrict__ w1a,
                                                    const float* __restrict__ b1a,
                                                    const float* __restrict__ w1b,
                                                    const float* __restrict__ b1b,
                                                    const float* __restrict__ be,
                                                    float* __restrict__ beff) {
    int t = blockIdx.x;
    const float* w1 = t ? w1b : w1a;
    const float* b1 = t ? b1b : b1a;
    for (int j = threadIdx.x; j < J400; j += blockDim.x) {
        int o = j / 25, y = (j / 5) % 5, x = j % 5;
        float acc = b1[o];
        if (t == 0) {
            for (int ey = 0; ey < 3; ey++) {
                int py = y + ey - 1; if (py < 0 || py > 4) continue;
                for (int ex = 0; ex < 3; ex++) {
                    int px = x + ex - 1; if (px < 0 || px > 4) continue;
                    for (int c1 = 0; c1 < CC; c1++)
                        acc += w1[((o * CC + c1) * 3 + ey) * 3 + ex] * be[c1];
                }
            }
        }
        beff[t * J400 + j] = acc;
    }
}

// ---- T[t][q][d][j=(o,y,x)] = composed conv1(conv_embed(onehot)) table -----
__global__ __launch_bounds__(256) void k_build_T(const float* __restrict__ w1a,
                                                 const float* __restrict__ w1b,
                                                 const float* __restrict__ A,
                                                 float* __restrict__ T) {
    int t = blockIdx.y;
    int qd = blockIdx.x;
    int d = qd % DICT, q = qd / DICT;
    int qy = q / 5, qx = q % 5;
    const float* w1 = t ? w1b : w1a;
    __shared__ float w1s[C1N * CC * 9];   // 36.9 KB
    __shared__ float As[CC * 9];          // 2.3 KB
    for (int i = threadIdx.x; i < C1N * CC * 9; i += 256) w1s[i] = w1[i];
    for (int i = threadIdx.x; i < CC * 9; i += 256) As[i] = A[d * CC * 9 + i];
    __syncthreads();
    float* Tout = T + (((size_t)t * 25 + q) * DICT + d) * J400;
    for (int j = threadIdx.x; j < J400; j += 256) {
        int o = j / 25, y = (j / 5) % 5, x = j % 5;
        float acc = 0.f;
        int py0 = max(0, max(y - 1, qy - 1)), py1 = min(4, min(y + 1, qy + 1));
        int px0 = max(0, max(x - 1, qx - 1)), px1 = min(4, min(x + 1, qx + 1));
        for (int py = py0; py <= py1; py++)
            for (int px = px0; px <= px1; px++) {
                int ey = py - y + 1, ex = px - x + 1;
                int fy = qy - py + 1, fx = qx - px + 1;
                const float* wp = &w1s[(o * CC) * 9 + (ey * 3 + ex)];
                const float* ap = &As[fy * 3 + fx];
                float pa = 0.f;
                #pragma unroll 8
                for (int c1 = 0; c1 < CC; c1++) pa += wp[c1 * 9] * ap[c1 * 9];
                acc += pa;
            }
        Tout[j] = acc;
    }
}

// ---- stage1: gather-sum tables -> relu(conv1 out) for both phis -----------
// output layout a1f[t][j][b]  (batch-minor, coalesced for conv2)
__global__ __launch_bounds__(256) void k_stage1(const int* __restrict__ s,
                                                const int* __restrict__ sp,
                                                const float* __restrict__ T,
                                                const float* __restrict__ beff,
                                                float* __restrict__ a1f) {
    __shared__ int s_sh[32][25], sp_sh[32][25];
    __shared__ float a_sh[32][J400 + 1];
    int b0 = blockIdx.x * 32;
    for (int i = threadIdx.x; i < 32 * 25; i += 256) {
        int si = i / 25, q = i % 25;
        s_sh[si][q]  = s[(b0 + si) * 25 + q];
        sp_sh[si][q] = sp[(b0 + si) * 25 + q];
    }
    __syncthreads();
    // phi1: beff1 + sum_q T1[q][s_q]
    for (int task = threadIdx.x; task < 32 * J400; task += 256) {
        int j = task % J400, si = task / J400;
        float acc = beff[j];
        #pragma unroll
        for (int q = 0; q < 25; q++) {
            int dq = s_sh[si][q];
            acc += T[(q * DICT + dq) * J400 + j];
        }
        a_sh[si][j] = fmaxf(acc, 0.f);
    }
    __syncthreads();
    for (int i = threadIdx.x; i < 32 * J400; i += 256) {
        int bl = i % 32, j = i / 32;
        a1f[(size_t)j * NB + b0 + bl] = a_sh[bl][j];
    }
    __syncthreads();
    // phi2: beff2 + sum_q (T2[q][s'_q] - T2[q][s_q])
    const float* T2 = T + 25 * DICT * J400;
    for (int task = threadIdx.x; task < 32 * J400; task += 256) {
        int j = task % J400, si = task / J400;
        float acc = beff[J400 + j];
        #pragma unroll
        for (int q = 0; q < 25; q++) {
            int dp = sp_sh[si][q], dq = s_sh[si][q];
            acc += T2[(q * DICT + dp) * J400 + j] - T2[(q * DICT + dq) * J400 + j];
        }
        a_sh[si][j] = fmaxf(acc, 0.f);
    }
    __syncthreads();
    for (int i = threadIdx.x; i < 32 * J400; i += 256) {
        int bl = i % 32, j = i / 32;
        a1f[(size_t)J400 * NB + (size_t)j * NB + b0 + bl] = a_sh[bl][j];
    }
}

// ---- conv2 (16->32, 3x3, 5x5) batch-vectorized, lane = batch --------------
__global__ __launch_bounds__(256) void k_conv2(const float* __restrict__ a1f,
                                               const float* __restrict__ w2a,
                                               const float* __restrict__ b2a,
                                               const float* __restrict__ w2b,
                                               const float* __restrict__ b2b,
                                               float* __restrict__ a2f) {
    int t = blockIdx.y;
    const float* w2  = t ? w2b : w2a;
    const float* b2  = t ? b2b : b2a;
    const float* in0 = a1f + (size_t)t * J400 * NB;
    float* out0      = a2f + (size_t)t * K800 * NB;
    int b  = blockIdx.x * 64 + (threadIdx.x & 63);
    int wv = threadIdx.x >> 6;                 // wave id: o2 group
    for (int o2g = 0; o2g < 8; o2g++) {
        int o2 = wv * 8 + o2g;
        float acc[25];
        float bias = b2[o2];
        #pragma unroll
        for (int p = 0; p < 25; p++) acc[p] = bias;
        for (int c1 = 0; c1 < C1N; c1++) {
            float in[25];
            #pragma unroll
            for (int p = 0; p < 25; p++) in[p] = in0[(size_t)(c1 * 25 + p) * NB + b];
            #pragma unroll
            for (int ky = 0; ky < 3; ky++)
            #pragma unroll
            for (int kx = 0; kx < 3; kx++) {
                float w = w2[((o2 * C1N + c1) * 3 + ky) * 3 + kx];
                #pragma unroll
                for (int y = 0; y < 5; y++) {
                    int iy = y + ky - 1; if (iy < 0 || iy > 4) continue;
                    #pragma unroll
                    for (int x = 0; x < 5; x++) {
                        int ix = x + kx - 1; if (ix < 0 || ix > 4) continue;
                        acc[y * 5 + x] += w * in[iy * 5 + ix];
                    }
                }
            }
        }
        #pragma unroll
        for (int p = 0; p < 25; p++)
            out0[(size_t)(o2 * 25 + p) * NB + b] = fmaxf(acc[p], 0.f);
    }
}

// ---- linear [B,800]@[800,256]+bias; A stored [k][B] (batch-minor) ---------
__global__ __launch_bounds__(256) void k_linear(const float* __restrict__ a2f,
                                                const float* __restrict__ lwa,
                                                const float* __restrict__ lba,
                                                const float* __restrict__ lwb,
                                                const float* __restrict__ lbb,
                                                float* __restrict__ embed) {
    int t = blockIdx.z;
    const float* Am   = a2f + (size_t)t * K800 * NB;
    const float* Wt   = t ? lwb : lwa;      // [256][800]
    const float* bias = t ? lbb : lba;
    float* Out        = embed + (size_t)t * NB * EDIM;
    int m0 = blockIdx.x * 128, n0 = blockIdx.y * 64;
    __shared__ float As[8][128];
    __shared__ float Bs[8][64];
    int tid = threadIdx.x;
    int tm = tid & 15, tn = tid >> 4;
    float acc[8][4] = {};
    for (int k0 = 0; k0 < K800; k0 += 8) {
        __syncthreads();
        {   // A tile 8x128
            int kk = tid >> 5, mm = (tid & 31) << 2;
            float4 v = *(const float4*)&Am[(size_t)(k0 + kk) * NB + m0 + mm];
            *(float4*)&As[kk][mm] = v;
        }
        {   // B tile 8x64 (transpose on store)
            int nn = tid & 63, kk = (tid >> 6) << 1;
            float2 v = *(const float2*)&Wt[(size_t)(n0 + nn) * K800 + k0 + kk];
            Bs[kk][nn] = v.x; Bs[kk + 1][nn] = v.y;
        }
        __syncthreads();
        #pragma unroll
        for (int kk = 0; kk < 8; kk++) {
            float af[8], bf[4];
            #pragma unroll
            for (int u = 0; u < 8; u++) af[u] = As[kk][tm * 8 + u];
            #pragma unroll
            for (int v = 0; v < 4; v++) bf[v] = Bs[kk][tn * 4 + v];
            #pragma unroll
            for (int u = 0; u < 8; u++)
                #pragma unroll
                for (int v = 0; v < 4; v++) acc[u][v] += af[u] * bf[v];
        }
    }
    #pragma unroll
    for (int u = 0; u < 8; u++) {
        size_t m = m0 + tm * 8 + u;
        float4 o;
        o.x = acc[u][0] + bias[n0 + tn * 4 + 0];
        o.y = acc[u][1] + bias[n0 + tn * 4 + 1];
        o.z = acc[u][2] + bias[n0 + tn * 4 + 2];
        o.w = acc[u][3] + bias[n0 + tn * 4 + 3];
        *(float4*)&Out[m * EDIM + n0 + tn * 4] = o;
    }
}

// ---- row-normalize embed: x / (||x|| + 1e-4) ------------------------------
__global__ __launch_bounds__(64) void k_normrows(float* __restrict__ embed) {
    int r = blockIdx.x, l = threadIdx.x;
    float* row = embed + (size_t)r * EDIM;
    float v0 = row[l], v1 = row[l + 64], v2 = row[l + 128], v3 = row[l + 192];
    float s = v0 * v0 + v1 * v1 + v2 * v2 + v3 * v3;
    #pragma unroll
    for (int o = 32; o > 0; o >>= 1) s += __shfl_down(s, o, 64);
    s = __shfl(s, 0, 64);
    float inv = 1.f / (sqrtf(s) + 1e-4f);
    row[l] = v0 * inv; row[l + 64] = v1 * inv; row[l + 128] = v2 * inv; row[l + 192] = v3 * inv;
}

// ---- scores/G0 GEMM: [16384,256]@[256,512] -> C ---------------------------
__global__ __launch_bounds__(256) void k_scores(const float* __restrict__ Ai,
                                                const float* __restrict__ Zn,
                                                float* __restrict__ C) {
    int m0 = blockIdx.x * 128, n0 = blockIdx.y * 64;
    __shared__ float As[8][128];
    __shared__ float Bs[8][64];
    int tid = threadIdx.x;
    int tm = tid & 15, tn = tid >> 4;
    float acc[8][4] = {};
    for (int k0 = 0; k0 < EDIM; k0 += 8) {
        __syncthreads();
        {   // A tile: rows m, 4 consecutive k per thread
            int mm = tid & 127, kk = (tid >> 7) << 2;
            float4 v = *(const float4*)&Ai[(size_t)(m0 + mm) * EDIM + k0 + kk];
            As[kk][mm] = v.x; As[kk + 1][mm] = v.y; As[kk + 2][mm] = v.z; As[kk + 3][mm] = v.w;
        }
        {
            int nn = tid & 63, kk = (tid >> 6) << 1;
            float2 v = *(const float2*)&Zn[(size_t)(n0 + nn) * EDIM + k0 + kk];
            Bs[kk][nn] = v.x; Bs[kk + 1][nn] = v.y;
        }
        __syncthreads();
        #pragma unroll
        for (int kk = 0; kk < 8; kk++) {
            float af[8], bf[4];
            #pragma unroll
            for (int u = 0; u < 8; u++) af[u] = As[kk][tm * 8 + u];
            #pragma unroll
            for (int v = 0; v < 4; v++) bf[v] = Bs[kk][tn * 4 + v];
            #pragma unroll
            for (int u = 0; u < 8; u++)
                #pragma unroll
                for (int v = 0; v < 4; v++) acc[u][v] += af[u] * bf[v];
        }
    }
    #pragma unroll
    for (int u = 0; u < 8; u++) {
        size_t m = m0 + tm * 8 + u;
        *(float4*)&C[m * NZV + n0 + tn * 4] = *(float4*)acc[u];
    }
}

// ---- argmax over scores rows (ties -> first index, matching jnp.argmax) ---
__global__ __launch_bounds__(64) void k_argmax(const float* __restrict__ C,
                                               int* __restrict__ idx) {
    int b = blockIdx.x, l = threadIdx.x;
    const float* row = C + (size_t)(NB + b) * NZV;
    float best = -3.0e38f; int bi = 0;
    for (int n = l; n < NZV; n += 64) {
        float v = row[n];
        if (v > best) { best = v; bi = n; }
    }
    #pragma unroll
    for (int o = 32; o > 0; o >>= 1) {
        float ov = __shfl_down(best, o, 64);
        int   oi = __shfl_down(bi, o, 64);
        if (ov > best || (ov == best && oi < bi)) { best = ov; bi = oi; }
    }
    if (l == 0) idx[b] = bi;
}

// ---- output: out[i][j] = exp(scale) * G0[i][idx[j]] -----------------------
__global__ __launch_bounds__(256) void k_out(const float* __restrict__ C,
                                             const int* __restrict__ idx,
                                             const float* __restrict__ scale,
                                             float* __restrict__ out) {
    __shared__ float g[8][NZV];     // 16 KB
    __shared__ int   id[2048];      // 8 KB
    int i0 = blockIdx.y * 8;
    int j0 = blockIdx.x * 2048;
    float esc = expf(scale[0]);
    for (int u = threadIdx.x; u < 2048; u += 256) id[u] = idx[j0 + u];
    for (int u = threadIdx.x; u < 8 * NZV; u += 256) {
        int r = u >> 9, c = u & 511;
        g[r][c] = C[(size_t)(i0 + r) * NZV + c];
    }
    __syncthreads();
    int jb = threadIdx.x * 8;
    int myid[8];
    #pragma unroll
    for (int u = 0; u < 8; u++) myid[u] = id[jb + u];
    #pragma unroll
    for (int r = 0; r < 8; r++) {
        float4 o0, o1;
        o0.x = esc * g[r][myid[0]]; o0.y = esc * g[r][myid[1]];
        o0.z = esc * g[r][myid[2]]; o0.w = esc * g[r][myid[3]];
        o1.x = esc * g[r][myid[4]]; o1.y = esc * g[r][myid[5]];
        o1.z = esc * g[r][myid[6]]; o1.w = esc * g[r][myid[7]];
        float4* dst = (float4*)(out + (size_t)(i0 + r) * NB + j0 + jb);
        dst[0] = o0; dst[1] = o1;
    }
}

extern "C" void kernel_launch(void* const* d_in, const int* in_sizes, int n_in,
                              void* d_out, int out_size, void* d_ws, size_t ws_size,
                              hipStream_t stream) {
    const int*   s     = (const int*)d_in[0];
    const int*   sp    = (const int*)d_in[1];
    const float* tab   = (const float*)d_in[2];
    const float* wE    = (const float*)d_in[3];
    const float* bE    = (const float*)d_in[4];
    const float* w1a   = (const float*)d_in[5];
    const float* b1a   = (const float*)d_in[6];
    const float* w2a   = (const float*)d_in[7];
    const float* b2a   = (const float*)d_in[8];
    const float* lwa   = (const float*)d_in[9];
    const float* lba   = (const float*)d_in[10];
    const float* w1b   = (const float*)d_in[11];
    const float* b1b   = (const float*)d_in[12];
    const float* w2b   = (const float*)d_in[13];
    const float* b2b   = (const float*)d_in[14];
    const float* lwb   = (const float*)d_in[15];
    const float* lbb   = (const float*)d_in[16];
    const float* zv    = (const float*)d_in[17];
    const float* scale = (const float*)d_in[18];

    float* out = (float*)d_out;
    float* wsf = (float*)d_ws;

    // d_ws layout (needs ~35.3 MB): tables + final C (G0|scores)
    float* tn   = wsf;                      // 448
    float* Aw   = wsf + 448;                // 8064
    float* beff = wsf + 8512;               // 800
    float* zn   = wsf + 9312;               // 131072
    int*   idx  = (int*)(wsf + 140384);     // 8192
    float* T    = wsf + 148576;             // 280000 (ends 428576)
    float* Cm   = wsf + 428800;             // 16384*512 = 8388608

    // d_out used as scratch for transients (fully overwritten by k_out):
    float* a1f = out;                       // 2*400*8192  = 6,553,600
    float* a2f = out + 6553600;             // 2*800*8192  = 13,107,200
    float* emb = out + 19660800;            // 2*8192*256  = 4,194,304 (ends 23,855,104)

    k_norm_embed<<<DICT, 64, 0, stream>>>(tab, tn);
    k_norm_z<<<NZV, 256, 0, stream>>>(zv, zn);
    k_build_A<<<32, 256, 0, stream>>>(wE, tn, Aw);
    k_build_beff<<<2, 256, 0, stream>>>(w1a, b1a, w1b, b1b, bE, beff);
    k_build_T<<<dim3(25 * DICT, 2), 256, 0, stream>>>(w1a, w1b, Aw, T);
    k_stage1<<<NB / 32, 256, 0, stream>>>(s, sp, T, beff, a1f);
    k_conv2<<<dim3(NB / 64, 2), 256, 0, stream>>>(a1f, w2a, b2a, w2b, b2b, a2f);
    k_linear<<<dim3(NB / 128, EDIM / 64, 2), 256, 0, stream>>>(a2f, lwa, lba, lwb, lbb, emb);
    k_normrows<<<2 * NB, 64, 0, stream>>>(emb);
    k_scores<<<dim3(2 * NB / 128, NZV / 64), 256, 0, stream>>>(emb, zn, Cm);
    k_argmax<<<NB, 64, 0, stream>>>(Cm, idx);
    k_out<<<dim3(NB / 2048, NB / 8), 256, 0, stream>>>(Cm, idx, scale, out);
}

// Round 2
// 609.853 us; speedup vs baseline: 1.1965x; 1.1965x over previous
//
#include <hip/hip_runtime.h>
#include <hip/hip_bf16.h>

#define NB    8192
#define DICT  14
#define SE    32
#define CC    64
#define EDIM  256
#define NZV   512
#define C1N   16
#define C2N   32
#define J400  400    // 16*25 (phi conv1 output, flattened o*25+pix)
#define K800  800    // 32*25 (phi conv2 output, flattened o*25+pix)

typedef __attribute__((ext_vector_type(8))) short bf16x8;
typedef __attribute__((ext_vector_type(4))) float f32x4;

// split fp32 -> bf16 hi (truncate) + bf16 lo (RNE of residual); 3-term MFMA
// product hh+hl+lh has ~2^-14 relative error (lo*lo dropped ~2^-18).
__device__ __forceinline__ void split_hl(float x, unsigned short& h, unsigned short& l) {
    unsigned u = __float_as_uint(x);
    unsigned short hh = (unsigned short)(u >> 16);
    float hf = __uint_as_float((unsigned)hh << 16);
    float lof = x - hf;
    unsigned ul = __float_as_uint(lof);
    l = (unsigned short)((ul + 0x7FFFu + ((ul >> 16) & 1u)) >> 16);
    h = hh;
}

// ---------------- prep: normalize embedding rows (max_norm=1 semantics) ----
__global__ __launch_bounds__(64) void k_norm_embed(const float* __restrict__ tab,
                                                   float* __restrict__ tn) {
    int d = blockIdx.x, l = threadIdx.x;
    float v = (l < SE) ? tab[d * SE + l] : 0.f;
    float s = v * v;
    #pragma unroll
    for (int o = 32; o > 0; o >>= 1) s += __shfl_down(s, o, 64);
    s = __shfl(s, 0, 64);
    float sc = fminf(1.f, 1.f / (sqrtf(s) + 1e-7f));
    if (l < SE) tn[d * SE + l] = v * sc;
}

// ---------------- prep: L2-normalize z_vectors (eps=0), emit hi/lo bf16 ----
__global__ __launch_bounds__(256) void k_norm_z(const float* __restrict__ z,
                                                unsigned short* __restrict__ znh,
                                                unsigned short* __restrict__ znl) {
    __shared__ float red[4];
    int r = blockIdx.x, t = threadIdx.x;
    float v = z[r * EDIM + t];
    float s = v * v;
    #pragma unroll
    for (int o = 32; o > 0; o >>= 1) s += __shfl_down(s, o, 64);
    if ((t & 63) == 0) red[t >> 6] = s;
    __syncthreads();
    float tot = red[0] + red[1] + red[2] + red[3];
    float nv = v / sqrtf(tot);
    unsigned short h, l;
    split_hl(nv, h, l);
    znh[r * EDIM + t] = h;
    znl[r * EDIM + t] = l;
}

// ---------------- prep: split linear weights to hi/lo bf16 [2][256][800] ---
__global__ __launch_bounds__(256) void k_prep_w(const float* __restrict__ lwa,
                                                const float* __restrict__ lwb,
                                                unsigned short* __restrict__ wh,
                                                unsigned short* __restrict__ wl) {
    int i = blockIdx.x * 256 + threadIdx.x;
    const int tot = 2 * EDIM * K800;
    if (i >= tot) return;
    float v = (i < EDIM * K800) ? lwa[i] : lwb[i - EDIM * K800];
    unsigned short h, l;
    split_hl(v, h, l);
    wh[i] = h; wl[i] = l;
}

// ---- A[d][c1][f] = sum_c0 We[c1,c0,f] * tn[d,c0]   (f = ky*3+kx) ----------
__global__ __launch_bounds__(256) void k_build_A(const float* __restrict__ we,
                                                 const float* __restrict__ tn,
                                                 float* __restrict__ A) {
    int i = blockIdx.x * 256 + threadIdx.x;
    if (i >= DICT * CC * 9) return;
    int f = i % 9, c1 = (i / 9) % CC, d = i / (9 * CC);
    float acc = 0.f;
    #pragma unroll
    for (int c0 = 0; c0 < SE; c0++) acc += we[(c1 * SE + c0) * 9 + f] * tn[d * SE + c0];
    A[i] = acc;
}

// ---- beff[t][j=(o,y,x)]: phi-conv1 effective bias. ------------------------
__global__ __launch_bounds__(256) void k_build_beff(const float* __restrict__ w1a,
                                                    const float* __restrict__ b1a,
                                                    const float* __restrict__ w1b,
                                                    const float* __restrict__ b1b,
                                                    const float* __restrict__ be,
                                                    float* __restrict__ beff) {
    int t = blockIdx.x;
    const float* w1 = t ? w1b : w1a;
    const float* b1 = t ? b1b : b1a;
    for (int j = threadIdx.x; j < J400; j += blockDim.x) {
        int o = j / 25, y = (j / 5) % 5, x = j % 5;
        float acc = b1[o];
        if (t == 0) {
            for (int ey = 0; ey < 3; ey++) {
                int py = y + ey - 1; if (py < 0 || py > 4) continue;
                for (int ex = 0; ex < 3; ex++) {
                    int px = x + ex - 1; if (px < 0 || px > 4) continue;
                    for (int c1 = 0; c1 < CC; c1++)
                        acc += w1[((o * CC + c1) * 3 + ey) * 3 + ex] * be[c1];
                }
            }
        }
        beff[t * J400 + j] = acc;
    }
}

// ---- T[t][q][d][j=(o,y,x)] = composed conv1(conv_embed(onehot)) table -----
__global__ __launch_bounds__(256) void k_build_T(const float* __restrict__ w1a,
                                                 const float* __restrict__ w1b,
                                                 const float* __restrict__ A,
                                                 float* __restrict__ T) {
    int t = blockIdx.y;
    int qd = blockIdx.x;
    int d = qd % DICT, q = qd / DICT;
    int qy = q / 5, qx = q % 5;
    const float* w1 = t ? w1b : w1a;
    __shared__ float w1s[C1N * CC * 9];
    __shared__ float As[CC * 9];
    for (int i = threadIdx.x; i < C1N * CC * 9; i += 256) w1s[i] = w1[i];
    for (int i = threadIdx.x; i < CC * 9; i += 256) As[i] = A[d * CC * 9 + i];
    __syncthreads();
    float* Tout = T + (((size_t)t * 25 + q) * DICT + d) * J400;
    for (int j = threadIdx.x; j < J400; j += 256) {
        int o = j / 25, y = (j / 5) % 5, x = j % 5;
        float acc = 0.f;
        int py0 = max(0, max(y - 1, qy - 1)), py1 = min(4, min(y + 1, qy + 1));
        int px0 = max(0, max(x - 1, qx - 1)), px1 = min(4, min(x + 1, qx + 1));
        for (int py = py0; py <= py1; py++)
            for (int px = px0; px <= px1; px++) {
                int ey = py - y + 1, ex = px - x + 1;
                int fy = qy - py + 1, fx = qx - px + 1;
                const float* wp = &w1s[(o * CC) * 9 + (ey * 3 + ex)];
                const float* ap = &As[fy * 3 + fx];
                float pa = 0.f;
                #pragma unroll 8
                for (int c1 = 0; c1 < CC; c1++) pa += wp[c1 * 9] * ap[c1 * 9];
                acc += pa;
            }
        Tout[j] = acc;
    }
}

// ---- stage1 (phi-split grid for 2 blocks/CU): table gather -> relu --------
__global__ __launch_bounds__(256) void k_stage1(const int* __restrict__ s,
                                                const int* __restrict__ sp,
                                                const float* __restrict__ T,
                                                const float* __restrict__ beff,
                                                float* __restrict__ a1f) {
    int phi = blockIdx.y;
    __shared__ int s_sh[32][25], sp_sh[32][25];
    __shared__ float a_sh[32][J400 + 1];
    int b0 = blockIdx.x * 32;
    for (int i = threadIdx.x; i < 32 * 25; i += 256) {
        int si = i / 25, q = i % 25;
        s_sh[si][q] = s[(b0 + si) * 25 + q];
        if (phi) sp_sh[si][q] = sp[(b0 + si) * 25 + q];
    }
    __syncthreads();
    const float* Tt = T + (size_t)phi * 25 * DICT * J400;
    const float* be = beff + phi * J400;
    if (phi == 0) {
        for (int task = threadIdx.x; task < 32 * J400; task += 256) {
            int j = task % J400, si = task / J400;
            float acc = be[j];
            #pragma unroll
            for (int q = 0; q < 25; q++)
                acc += Tt[(q * DICT + s_sh[si][q]) * J400 + j];
            a_sh[si][j] = fmaxf(acc, 0.f);
        }
    } else {
        for (int task = threadIdx.x; task < 32 * J400; task += 256) {
            int j = task % J400, si = task / J400;
            float acc = be[j];
            #pragma unroll
            for (int q = 0; q < 25; q++)
                acc += Tt[(q * DICT + sp_sh[si][q]) * J400 + j]
                     - Tt[(q * DICT + s_sh[si][q]) * J400 + j];
            a_sh[si][j] = fmaxf(acc, 0.f);
        }
    }
    __syncthreads();
    float* outp = a1f + (size_t)phi * J400 * NB;
    for (int i = threadIdx.x; i < 32 * J400; i += 256) {
        int bl = i % 32, j = i / 32;
        outp[(size_t)j * NB + b0 + bl] = a_sh[bl][j];
    }
}

// ---- conv2 (16->32, 3x3, 5x5), z-split for 2 blocks/CU --------------------
__global__ __launch_bounds__(256) void k_conv2(const float* __restrict__ a1f,
                                               const float* __restrict__ w2a,
                                               const float* __restrict__ b2a,
                                               const float* __restrict__ w2b,
                                               const float* __restrict__ b2b,
                                               float* __restrict__ a2f) {
    int t = blockIdx.y;
    const float* w2  = t ? w2b : w2a;
    const float* b2  = t ? b2b : b2a;
    const float* in0 = a1f + (size_t)t * J400 * NB;
    float* out0      = a2f + (size_t)t * K800 * NB;
    int b  = blockIdx.x * 64 + (threadIdx.x & 63);
    int og = blockIdx.z * 4 + (threadIdx.x >> 6);   // 0..7
    for (int o2g = 0; o2g < 4; o2g++) {
        int o2 = og * 4 + o2g;
        float acc[25];
        float bias = b2[o2];
        #pragma unroll
        for (int p = 0; p < 25; p++) acc[p] = bias;
        for (int c1 = 0; c1 < C1N; c1++) {
            float in[25];
            #pragma unroll
            for (int p = 0; p < 25; p++) in[p] = in0[(size_t)(c1 * 25 + p) * NB + b];
            #pragma unroll
            for (int ky = 0; ky < 3; ky++)
            #pragma unroll
            for (int kx = 0; kx < 3; kx++) {
                float w = w2[((o2 * C1N + c1) * 3 + ky) * 3 + kx];
                #pragma unroll
                for (int y = 0; y < 5; y++) {
                    int iy = y + ky - 1; if (iy < 0 || iy > 4) continue;
                    #pragma unroll
                    for (int x = 0; x < 5; x++) {
                        int ix = x + kx - 1; if (ix < 0 || ix > 4) continue;
                        acc[y * 5 + x] += w * in[iy * 5 + ix];
                    }
                }
            }
        }
        #pragma unroll
        for (int p = 0; p < 25; p++)
            out0[(size_t)(o2 * 25 + p) * NB + b] = fmaxf(acc[p], 0.f);
    }
}

// ---- linear via split-bf16 MFMA, fused row-norm, emits eh/el bf16 ---------
// block: 32 batches x all N=256 (4 waves, each 64 n). A staged via LDS
// transpose+split from k-major fp32 a2f. D = Ah*Bh + Ah*Bl + Al*Bh.
__global__ __launch_bounds__(256) void k_linear_mfma(const float* __restrict__ a2f,
        const unsigned short* __restrict__ wh, const unsigned short* __restrict__ wl,
        const float* __restrict__ lba, const float* __restrict__ lbb,
        unsigned short* __restrict__ eh, unsigned short* __restrict__ el) {
    int phi = blockIdx.y;
    const float* Am = a2f + (size_t)phi * K800 * NB;
    const unsigned short* Wh = wh + (size_t)phi * EDIM * K800;
    const unsigned short* Wl = wl + (size_t)phi * EDIM * K800;
    const float* bias = phi ? lbb : lba;
    int b0 = blockIdx.x * 32;
    int tid = threadIdx.x;
    int wv = tid >> 6, lane = tid & 63, li = lane & 15, quad = lane >> 4;
    int n0 = wv * 64;
    int sb = tid & 31, kc = (tid >> 5) * 4;
    __shared__ __align__(16) unsigned short AhS[32][40], AlS[32][40];  // pad 32->40
    __shared__ float red[32][4];
    f32x4 acc[2][4];
    f32x4 zz = {0.f, 0.f, 0.f, 0.f};
    #pragma unroll
    for (int i = 0; i < 2; i++)
        #pragma unroll
        for (int j = 0; j < 4; j++) acc[i][j] = zz;

    for (int k0 = 0; k0 < K800; k0 += 32) {
        float x0 = Am[(size_t)(k0 + kc + 0) * NB + b0 + sb];
        float x1 = Am[(size_t)(k0 + kc + 1) * NB + b0 + sb];
        float x2 = Am[(size_t)(k0 + kc + 2) * NB + b0 + sb];
        float x3 = Am[(size_t)(k0 + kc + 3) * NB + b0 + sb];
        __syncthreads();   // previous iteration's frag reads complete
        unsigned short h0, l0, h1, l1, h2, l2, h3, l3;
        split_hl(x0, h0, l0); split_hl(x1, h1, l1);
        split_hl(x2, h2, l2); split_hl(x3, h3, l3);
        *(ushort4*)&AhS[sb][kc] = make_ushort4(h0, h1, h2, h3);
        *(ushort4*)&AlS[sb][kc] = make_ushort4(l0, l1, l2, l3);
        __syncthreads();
        bf16x8 ah0 = *(const bf16x8*)&AhS[li][quad * 8];
        bf16x8 ah1 = *(const bf16x8*)&AhS[16 + li][quad * 8];
        bf16x8 al0 = *(const bf16x8*)&AlS[li][quad * 8];
        bf16x8 al1 = *(const bf16x8*)&AlS[16 + li][quad * 8];
        #pragma unroll
        for (int nt = 0; nt < 4; nt++) {
            size_t wo = (size_t)(n0 + nt * 16 + li) * K800 + k0 + quad * 8;
            bf16x8 bh = *(const bf16x8*)(Wh + wo);
            bf16x8 bl = *(const bf16x8*)(Wl + wo);
            acc[0][nt] = __builtin_amdgcn_mfma_f32_16x16x32_bf16(ah0, bh, acc[0][nt], 0, 0, 0);
            acc[0][nt] = __builtin_amdgcn_mfma_f32_16x16x32_bf16(ah0, bl, acc[0][nt], 0, 0, 0);
            acc[0][nt] = __builtin_amdgcn_mfma_f32_16x16x32_bf16(al0, bh, acc[0][nt], 0, 0, 0);
            acc[1][nt] = __builtin_amdgcn_mfma_f32_16x16x32_bf16(ah1, bh, acc[1][nt], 0, 0, 0);
            acc[1][nt] = __builtin_amdgcn_mfma_f32_16x16x32_bf16(ah1, bl, acc[1][nt], 0, 0, 0);
            acc[1][nt] = __builtin_amdgcn_mfma_f32_16x16x32_bf16(al1, bh, acc[1][nt], 0, 0, 0);
        }
    }
    // bias add + per-row sum of squares (this wave's 64 cols)
    float q[2][4];
    #pragma unroll
    for (int mt = 0; mt < 2; mt++)
        #pragma unroll
        for (int r = 0; r < 4; r++) q[mt][r] = 0.f;
    #pragma unroll
    for (int mt = 0; mt < 2; mt++)
        #pragma unroll
        for (int nt = 0; nt < 4; nt++) {
            float bsv = bias[n0 + nt * 16 + li];
            #pragma unroll
            for (int r = 0; r < 4; r++) {
                float v = acc[mt][nt][r] + bsv;
                acc[mt][nt][r] = v;
                q[mt][r] += v * v;
            }
        }
    #pragma unroll
    for (int off = 1; off < 16; off <<= 1) {
        #pragma unroll
        for (int mt = 0; mt < 2; mt++)
            #pragma unroll
            for (int r = 0; r < 4; r++)
                q[mt][r] += __shfl_xor(q[mt][r], off, 64);
    }
    if (li == 0) {
        #pragma unroll
        for (int mt = 0; mt < 2; mt++)
            #pragma unroll
            for (int r = 0; r < 4; r++)
                red[mt * 16 + quad * 4 + r][wv] = q[mt][r];
    }
    __syncthreads();
    #pragma unroll
    for (int mt = 0; mt < 2; mt++) {
        #pragma unroll
        for (int r = 0; r < 4; r++) {
            int row = mt * 16 + quad * 4 + r;
            float tot = red[row][0] + red[row][1] + red[row][2] + red[row][3];
            float inv = 1.f / (sqrtf(tot) + 1e-4f);
            size_t base = (size_t)(phi * NB + b0 + row) * EDIM;
            #pragma unroll
            for (int nt = 0; nt < 4; nt++) {
                float v = acc[mt][nt][r] * inv;
                unsigned short h, l;
                split_hl(v, h, l);
                eh[base + n0 + nt * 16 + li] = h;
                el[base + n0 + nt * 16 + li] = l;
            }
        }
    }
}

// ---- scores via split-bf16 MFMA: [16384,256] x [512,256]^T -> Cm fp32 -----
__global__ __launch_bounds__(256) void k_scores_mfma(const unsigned short* __restrict__ eh,
        const unsigned short* __restrict__ el,
        const unsigned short* __restrict__ znh, const unsigned short* __restrict__ znl,
        float* __restrict__ C) {
    int m0 = blockIdx.x * 64;
    int wv = threadIdx.x >> 6, lane = threadIdx.x & 63;
    int li = lane & 15, quad = lane >> 4;
    int n0 = blockIdx.y * 256 + wv * 64;
    f32x4 acc[4][4];
    f32x4 zz = {0.f, 0.f, 0.f, 0.f};
    #pragma unroll
    for (int i = 0; i < 4; i++)
        #pragma unroll
        for (int j = 0; j < 4; j++) acc[i][j] = zz;
    for (int k0 = 0; k0 < EDIM; k0 += 32) {
        bf16x8 ah[4], al[4];
        #pragma unroll
        for (int mt = 0; mt < 4; mt++) {
            size_t ao = (size_t)(m0 + mt * 16 + li) * EDIM + k0 + quad * 8;
            ah[mt] = *(const bf16x8*)(eh + ao);
            al[mt] = *(const bf16x8*)(el + ao);
        }
        #pragma unroll
        for (int nt = 0; nt < 4; nt++) {
            size_t bo = (size_t)(n0 + nt * 16 + li) * EDIM + k0 + quad * 8;
            bf16x8 bh = *(const bf16x8*)(znh + bo);
            bf16x8 bl = *(const bf16x8*)(znl + bo);
            #pragma unroll
            for (int mt = 0; mt < 4; mt++) {
                acc[mt][nt] = __builtin_amdgcn_mfma_f32_16x16x32_bf16(ah[mt], bh, acc[mt][nt], 0, 0, 0);
                acc[mt][nt] = __builtin_amdgcn_mfma_f32_16x16x32_bf16(ah[mt], bl, acc[mt][nt], 0, 0, 0);
                acc[mt][nt] = __builtin_amdgcn_mfma_f32_16x16x32_bf16(al[mt], bh, acc[mt][nt], 0, 0, 0);
            }
        }
    }
    #pragma unroll
    for (int mt = 0; mt < 4; mt++)
        #pragma unroll
        for (int nt = 0; nt < 4; nt++)
            #pragma unroll
            for (int r = 0; r < 4; r++)
                C[(size_t)(m0 + mt * 16 + quad * 4 + r) * NZV + n0 + nt * 16 + li] = acc[mt][nt][r];
}

// ---- argmax over scores rows (ties -> first index, matching jnp.argmax) ---
__global__ __launch_bounds__(64) void k_argmax(const float* __restrict__ C,
                                               int* __restrict__ idx) {
    int b = blockIdx.x, l = threadIdx.x;
    const float* row = C + (size_t)(NB + b) * NZV;
    float best = -3.0e38f; int bi = 0;
    for (int n = l; n < NZV; n += 64) {
        float v = row[n];
        if (v > best) { best = v; bi = n; }
    }
    #pragma unroll
    for (int o = 32; o > 0; o >>= 1) {
        float ov = __shfl_down(best, o, 64);
        int   oi = __shfl_down(bi, o, 64);
        if (ov > best || (ov == best && oi < bi)) { best = ov; bi = oi; }
    }
    if (l == 0) idx[b] = bi;
}

// ---- output: out[i][j] = exp(scale) * G0[i][idx[j]] -----------------------
__global__ __launch_bounds__(256) void k_out(const float* __restrict__ C,
                                             const int* __restrict__ idx,
                                             const float* __restrict__ scale,
                                             float* __restrict__ out) {
    __shared__ float g[8][NZV];
    __shared__ int   id[2048];
    int i0 = blockIdx.y * 8;
    int j0 = blockIdx.x * 2048;
    float esc = expf(scale[0]);
    for (int u = threadIdx.x; u < 2048; u += 256) id[u] = idx[j0 + u];
    for (int u = threadIdx.x; u < 8 * NZV; u += 256) {
        int r = u >> 9, c = u & 511;
        g[r][c] = C[(size_t)(i0 + r) * NZV + c];
    }
    __syncthreads();
    int jb = threadIdx.x * 8;
    int myid[8];
    #pragma unroll
    for (int u = 0; u < 8; u++) myid[u] = id[jb + u];
    #pragma unroll
    for (int r = 0; r < 8; r++) {
        float4 o0, o1;
        o0.x = esc * g[r][myid[0]]; o0.y = esc * g[r][myid[1]];
        o0.z = esc * g[r][myid[2]]; o0.w = esc * g[r][myid[3]];
        o1.x = esc * g[r][myid[4]]; o1.y = esc * g[r][myid[5]];
        o1.z = esc * g[r][myid[6]]; o1.w = esc * g[r][myid[7]];
        float4* dst = (float4*)(out + (size_t)(i0 + r) * NB + j0 + jb);
        dst[0] = o0; dst[1] = o1;
    }
}

extern "C" void kernel_launch(void* const* d_in, const int* in_sizes, int n_in,
                              void* d_out, int out_size, void* d_ws, size_t ws_size,
                              hipStream_t stream) {
    const int*   s     = (const int*)d_in[0];
    const int*   sp    = (const int*)d_in[1];
    const float* tab   = (const float*)d_in[2];
    const float* wE    = (const float*)d_in[3];
    const float* bE    = (const float*)d_in[4];
    const float* w1a   = (const float*)d_in[5];
    const float* b1a   = (const float*)d_in[6];
    const float* w2a   = (const float*)d_in[7];
    const float* b2a   = (const float*)d_in[8];
    const float* lwa   = (const float*)d_in[9];
    const float* lba   = (const float*)d_in[10];
    const float* w1b   = (const float*)d_in[11];
    const float* b1b   = (const float*)d_in[12];
    const float* w2b   = (const float*)d_in[13];
    const float* b2b   = (const float*)d_in[14];
    const float* lwb   = (const float*)d_in[15];
    const float* lbb   = (const float*)d_in[16];
    const float* zv    = (const float*)d_in[17];
    const float* scale = (const float*)d_in[18];

    float* out = (float*)d_out;
    float* wsf = (float*)d_ws;

    // d_ws layout (float units), ~53.7 MB total
    float* tn   = wsf;                         // 448
    float* Aw   = wsf + 448;                   // 8064
    float* beff = wsf + 8512;                  // 800
    int*   idx  = (int*)(wsf + 9312);          // 8192
    float* T    = wsf + 17504;                 // 280000
    float* Cm   = wsf + 297504;                // 8388608 -> ends 8686112
    unsigned short* znh = (unsigned short*)(wsf + 8686112);   // 131072 u16
    unsigned short* znl = (unsigned short*)(wsf + 8751648);
    unsigned short* wh  = (unsigned short*)(wsf + 8817184);   // 409600 u16
    unsigned short* wl  = (unsigned short*)(wsf + 9021984);
    unsigned short* eh  = (unsigned short*)(wsf + 9226784);   // 4194304 u16
    unsigned short* el  = (unsigned short*)(wsf + 11323936);  // ends 13421088

    // d_out as scratch (dead before k_out fully overwrites it)
    float* a1f = out;                          // 2*400*8192
    float* a2f = out + 6553600;                // 2*800*8192

    k_norm_embed<<<DICT, 64, 0, stream>>>(tab, tn);
    k_norm_z<<<NZV, 256, 0, stream>>>(zv, znh, znl);
    k_prep_w<<<1600, 256, 0, stream>>>(lwa, lwb, wh, wl);
    k_build_A<<<32, 256, 0, stream>>>(wE, tn, Aw);
    k_build_beff<<<2, 256, 0, stream>>>(w1a, b1a, w1b, b1b, bE, beff);
    k_build_T<<<dim3(25 * DICT, 2), 256, 0, stream>>>(w1a, w1b, Aw, T);
    k_stage1<<<dim3(NB / 32, 2), 256, 0, stream>>>(s, sp, T, beff, a1f);
    k_conv2<<<dim3(NB / 64, 2, 2), 256, 0, stream>>>(a1f, w2a, b2a, w2b, b2b, a2f);
    k_linear_mfma<<<dim3(NB / 32, 2), 256, 0, stream>>>(a2f, wh, wl, lba, lbb, eh, el);
    k_scores_mfma<<<dim3(2 * NB / 64, NZV / 256), 256, 0, stream>>>(eh, el, znh, znl, Cm);
    k_argmax<<<NB, 64, 0, stream>>>(Cm, idx);
    k_out<<<dim3(NB / 2048, NB / 8), 256, 0, stream>>>(Cm, idx, scale, out);
}

// Round 3
// 531.049 us; speedup vs baseline: 1.3740x; 1.1484x over previous
//
#include <hip/hip_runtime.h>
#include <hip/hip_bf16.h>

#define NB    8192
#define DICT  14
#define SE    32
#define CC    64
#define EDIM  256
#define NZV   512
#define C1N   16
#define C2N   32

typedef __attribute__((ext_vector_type(8))) short bf16x8;
typedef __attribute__((ext_vector_type(4))) float f32x4;

// split fp32 -> bf16 hi (truncate) + bf16 lo (RNE of residual); 3-term MFMA
__device__ __forceinline__ void split_hl(float x, unsigned short& h, unsigned short& l) {
    unsigned u = __float_as_uint(x);
    unsigned short hh = (unsigned short)(u >> 16);
    float hf = __uint_as_float((unsigned)hh << 16);
    float lof = x - hf;
    unsigned ul = __float_as_uint(lof);
    l = (unsigned short)((ul + 0x7FFFu + ((ul >> 16) & 1u)) >> 16);
    h = hh;
}

// ---------------- prep: normalize embedding rows (max_norm=1) --------------
__global__ __launch_bounds__(64) void k_norm_embed(const float* __restrict__ tab,
                                                   float* __restrict__ tn) {
    int d = blockIdx.x, l = threadIdx.x;
    float v = (l < SE) ? tab[d * SE + l] : 0.f;
    float s = v * v;
    #pragma unroll
    for (int o = 32; o > 0; o >>= 1) s += __shfl_down(s, o, 64);
    s = __shfl(s, 0, 64);
    float sc = fminf(1.f, 1.f / (sqrtf(s) + 1e-7f));
    if (l < SE) tn[d * SE + l] = v * sc;
}

// ---- norm z (h/l bf16) + split linear weights, one launch -----------------
__global__ __launch_bounds__(256) void k_prep_zw(const float* __restrict__ z,
        const float* __restrict__ lwa, const float* __restrict__ lwb,
        unsigned short* __restrict__ znh, unsigned short* __restrict__ znl,
        unsigned short* __restrict__ wh, unsigned short* __restrict__ wl) {
    int bid = blockIdx.x, t = threadIdx.x;
    if (bid < NZV) {
        __shared__ float red[4];
        float v = z[bid * EDIM + t];
        float s = v * v;
        #pragma unroll
        for (int o = 32; o > 0; o >>= 1) s += __shfl_down(s, o, 64);
        if ((t & 63) == 0) red[t >> 6] = s;
        __syncthreads();
        float tot = red[0] + red[1] + red[2] + red[3];
        float nv = v / sqrtf(tot);
        unsigned short h, l;
        split_hl(nv, h, l);
        znh[bid * EDIM + t] = h;
        znl[bid * EDIM + t] = l;
    } else {
        int i = (bid - NZV) * 256 + t;            // [2][256][800]
        if (i < 2 * EDIM * 800) {
            float v = (i < EDIM * 800) ? lwa[i] : lwb[i - EDIM * 800];
            unsigned short h, l;
            split_hl(v, h, l);
            wh[i] = h; wl[i] = l;
        }
    }
}

// ---- build_A + build_beff merged ------------------------------------------
__global__ __launch_bounds__(256) void k_prep_ab(const float* __restrict__ we,
        const float* __restrict__ tn,
        const float* __restrict__ w1a, const float* __restrict__ b1a,
        const float* __restrict__ w1b, const float* __restrict__ b1b,
        const float* __restrict__ be,
        float* __restrict__ A, float* __restrict__ beff) {
    if (blockIdx.x < 32) {
        int i = blockIdx.x * 256 + threadIdx.x;
        if (i >= DICT * CC * 9) return;
        int f = i % 9, c1 = (i / 9) % CC, d = i / (9 * CC);
        float acc = 0.f;
        #pragma unroll
        for (int c0 = 0; c0 < SE; c0++) acc += we[(c1 * SE + c0) * 9 + f] * tn[d * SE + c0];
        A[i] = acc;
    } else {
        int t = blockIdx.x - 32;
        const float* w1 = t ? w1b : w1a;
        const float* b1 = t ? b1b : b1a;
        for (int j = threadIdx.x; j < 400; j += blockDim.x) {
            int o = j / 25, y = (j / 5) % 5, x = j % 5;
            float acc = b1[o];
            if (t == 0) {
                for (int ey = 0; ey < 3; ey++) {
                    int py = y + ey - 1; if (py < 0 || py > 4) continue;
                    for (int ex = 0; ex < 3; ex++) {
                        int px = x + ex - 1; if (px < 0 || px > 4) continue;
                        for (int c1 = 0; c1 < CC; c1++)
                            acc += w1[((o * CC + c1) * 3 + ey) * 3 + ex] * be[c1];
                    }
                }
            }
            beff[t * 400 + j] = acc;
        }
    }
}

// ---- T[t][q][d][j] = composed conv1(conv_embed(onehot)) table -------------
__global__ __launch_bounds__(256) void k_build_T(const float* __restrict__ w1a,
                                                 const float* __restrict__ w1b,
                                                 const float* __restrict__ A,
                                                 float* __restrict__ T) {
    int t = blockIdx.y;
    int qd = blockIdx.x;
    int d = qd % DICT, q = qd / DICT;
    int qy = q / 5, qx = q % 5;
    const float* w1 = t ? w1b : w1a;
    __shared__ float w1s[C1N * CC * 9];
    __shared__ float As[CC * 9];
    for (int i = threadIdx.x; i < C1N * CC * 9; i += 256) w1s[i] = w1[i];
    for (int i = threadIdx.x; i < CC * 9; i += 256) As[i] = A[d * CC * 9 + i];
    __syncthreads();
    float* Tout = T + (((size_t)t * 25 + q) * DICT + d) * 400;
    for (int j = threadIdx.x; j < 400; j += 256) {
        int o = j / 25, y = (j / 5) % 5, x = j % 5;
        float acc = 0.f;
        int py0 = max(0, max(y - 1, qy - 1)), py1 = min(4, min(y + 1, qy + 1));
        int px0 = max(0, max(x - 1, qx - 1)), px1 = min(4, min(x + 1, qx + 1));
        for (int py = py0; py <= py1; py++)
            for (int px = px0; px <= px1; px++) {
                int ey = py - y + 1, ex = px - x + 1;
                int fy = qy - py + 1, fx = qx - px + 1;
                const float* wp = &w1s[(o * CC) * 9 + (ey * 3 + ex)];
                const float* ap = &As[fy * 3 + fx];
                float pa = 0.f;
                #pragma unroll 8
                for (int c1 = 0; c1 < CC; c1++) pa += wp[c1 * 9] * ap[c1 * 9];
                acc += pa;
            }
        Tout[j] = acc;
    }
}

// ===================== mega-kernel: phi pipeline ===========================
// Per (32-sample tile, phi): table-gather conv1 -> conv2 -> linear+norm ->
// scores; phi1 writes G0 rows to Cm, phi2 computes argmax -> idx.
// All intermediates live in LDS.  2 blocks/CU (79.9 KB LDS).
__global__ __launch_bounds__(256, 2) void k_phi(
    const int* __restrict__ s, const int* __restrict__ sp,
    const float* __restrict__ T, const float* __restrict__ beff,
    const float* __restrict__ w2a, const float* __restrict__ b2a,
    const float* __restrict__ w2b, const float* __restrict__ b2b,
    const unsigned short* __restrict__ wh, const unsigned short* __restrict__ wl,
    const float* __restrict__ lba, const float* __restrict__ lbb,
    const unsigned short* __restrict__ znh, const unsigned short* __restrict__ znl,
    float* __restrict__ Cm, int* __restrict__ idxout) {
    int phi = blockIdx.y;
    int b0 = blockIdx.x * 32;
    int tid = threadIdx.x;
    int wv = tid >> 6, lane = tid & 63, li = lane & 15, quad = lane >> 4;

    __shared__ __align__(16) char smem[79936];
    float* a1T          = (float*)smem;                          // [400][33] f32
    unsigned short* a2h = (unsigned short*)(smem + 52800);       // [32][200]
    unsigned short* a2l = (unsigned short*)(smem + 65600);       // [32][200]
    int* sbase1         = (int*)(smem + 52800);                  // overlay (phase A only)
    int* sbase2         = (int*)(smem + 56000);
    float* redq         = (float*)(smem + 78400);                // [32][4]
    float* argv         = (float*)(smem + 78912);                // [32][4]
    int*   argn         = (int*)(smem + 79424);                  // [32][4]
    unsigned short* emh = (unsigned short*)smem;                 // overlay a1T: [32][264]
    unsigned short* eml = (unsigned short*)(smem + 16896);

    const float* Tg = T + (size_t)phi * (25 * DICT * 400);

    // ---- load index bases (premultiplied T row offsets) ----
    for (int i = tid; i < 800; i += 256) {
        int si = i / 25, q = i - si * 25;
        sbase1[i] = (q * DICT + s[(b0 + si) * 25 + q]) * 400;
        if (phi) sbase2[i] = (q * DICT + sp[(b0 + si) * 25 + q]) * 400;
    }
    __syncthreads();

    // ---- phase A: conv1 via table gather -> a1T[j][si] (relu'd fp32) ----
    const float* be = beff + phi * 400;
    if (phi == 0) {
        for (int task = tid; task < 12800; task += 256) {
            int si = task / 400, j = task - si * 400;
            float acc = be[j];
            const int* sb = sbase1 + si * 25;
            #pragma unroll
            for (int q = 0; q < 25; q++) acc += Tg[sb[q] + j];
            a1T[j * 33 + si] = fmaxf(acc, 0.f);
        }
    } else {
        for (int task = tid; task < 12800; task += 256) {
            int si = task / 400, j = task - si * 400;
            float acc = be[j];
            const int* sb1 = sbase1 + si * 25;
            const int* sb2 = sbase2 + si * 25;
            #pragma unroll
            for (int q = 0; q < 25; q++) acc += Tg[sb2[q] + j] - Tg[sb1[q] + j];
            a1T[j * 33 + si] = fmaxf(acc, 0.f);
        }
    }
    __syncthreads();   // sbase dead; a2 region reusable

    // ---- phases B+GEMM2: conv2 chunks (8 o2 = 200 k) -> linear accum ----
    const float* w2 = phi ? w2b : w2a;
    const float* b2 = phi ? b2b : b2a;
    const unsigned short* Wh = wh + (size_t)phi * EDIM * 800;
    const unsigned short* Wl = wl + (size_t)phi * EDIM * 800;
    int n0w = wv * 64;
    f32x4 acc2[2][4];
    f32x4 zz = {0.f, 0.f, 0.f, 0.f};
    #pragma unroll
    for (int i = 0; i < 2; i++)
        #pragma unroll
        for (int j = 0; j < 4; j++) acc2[i][j] = zz;
    bf16x8 zfrag = {0, 0, 0, 0, 0, 0, 0, 0};

    int csi = tid >> 3, o2loc = tid & 7;
    for (int c = 0; c < 4; c++) {
        // conv2 for this thread's (si, o2)
        int o2 = c * 8 + o2loc;
        float cacc[25];
        float bias2 = b2[o2];
        #pragma unroll
        for (int p = 0; p < 25; p++) cacc[p] = bias2;
        for (int c1 = 0; c1 < C1N; c1++) {
            float row[25];
            #pragma unroll
            for (int p = 0; p < 25; p++) row[p] = a1T[(c1 * 25 + p) * 33 + csi];
            #pragma unroll
            for (int ky = 0; ky < 3; ky++)
            #pragma unroll
            for (int kx = 0; kx < 3; kx++) {
                float w = w2[((o2 * C1N + c1) * 3 + ky) * 3 + kx];
                #pragma unroll
                for (int y = 0; y < 5; y++) {
                    int iy = y + ky - 1; if (iy < 0 || iy > 4) continue;
                    #pragma unroll
                    for (int x = 0; x < 5; x++) {
                        int ix = x + kx - 1; if (ix < 0 || ix > 4) continue;
                        cacc[y * 5 + x] += w * row[iy * 5 + ix];
                    }
                }
            }
        }
        #pragma unroll
        for (int p = 0; p < 25; p++) {
            float v = fmaxf(cacc[p], 0.f);
            unsigned short h, l;
            split_hl(v, h, l);
            int ko = csi * 200 + o2loc * 25 + p;
            a2h[ko] = h; a2l[ko] = l;
        }
        __syncthreads();
        // GEMM2 partial-K: 6 full steps + 1 partial (kloc 192..199)
        #pragma unroll
        for (int ks = 0; ks < 7; ks++) {
            bf16x8 ah0, al0, ah1, al1;
            if (ks < 6) {
                int ko = ks * 32 + quad * 8;
                ah0 = *(const bf16x8*)&a2h[li * 200 + ko];
                al0 = *(const bf16x8*)&a2l[li * 200 + ko];
                ah1 = *(const bf16x8*)&a2h[(16 + li) * 200 + ko];
                al1 = *(const bf16x8*)&a2l[(16 + li) * 200 + ko];
            } else {
                ah0 = zfrag; al0 = zfrag; ah1 = zfrag; al1 = zfrag;
                if (quad == 0) {
                    ah0 = *(const bf16x8*)&a2h[li * 200 + 192];
                    al0 = *(const bf16x8*)&a2l[li * 200 + 192];
                    ah1 = *(const bf16x8*)&a2h[(16 + li) * 200 + 192];
                    al1 = *(const bf16x8*)&a2l[(16 + li) * 200 + 192];
                }
            }
            int kglob = c * 200 + ks * 32 + quad * 8;
            #pragma unroll
            for (int nt = 0; nt < 4; nt++) {
                size_t wo = (size_t)(n0w + nt * 16 + li) * 800 + kglob;
                bf16x8 bh = *(const bf16x8*)(Wh + wo);
                bf16x8 bl = *(const bf16x8*)(Wl + wo);
                acc2[0][nt] = __builtin_amdgcn_mfma_f32_16x16x32_bf16(ah0, bh, acc2[0][nt], 0, 0, 0);
                acc2[0][nt] = __builtin_amdgcn_mfma_f32_16x16x32_bf16(ah0, bl, acc2[0][nt], 0, 0, 0);
                acc2[0][nt] = __builtin_amdgcn_mfma_f32_16x16x32_bf16(al0, bh, acc2[0][nt], 0, 0, 0);
                acc2[1][nt] = __builtin_amdgcn_mfma_f32_16x16x32_bf16(ah1, bh, acc2[1][nt], 0, 0, 0);
                acc2[1][nt] = __builtin_amdgcn_mfma_f32_16x16x32_bf16(ah1, bl, acc2[1][nt], 0, 0, 0);
                acc2[1][nt] = __builtin_amdgcn_mfma_f32_16x16x32_bf16(al1, bh, acc2[1][nt], 0, 0, 0);
            }
        }
        __syncthreads();   // a2 consumed before next chunk overwrites
    }

    // ---- phase C: bias + row-normalize + split -> embed h/l in LDS ----
    const float* lb = phi ? lbb : lba;
    float sq[2][4];
    #pragma unroll
    for (int mt = 0; mt < 2; mt++)
        #pragma unroll
        for (int r = 0; r < 4; r++) sq[mt][r] = 0.f;
    #pragma unroll
    for (int mt = 0; mt < 2; mt++)
        #pragma unroll
        for (int nt = 0; nt < 4; nt++) {
            float bsv = lb[n0w + nt * 16 + li];
            #pragma unroll
            for (int r = 0; r < 4; r++) {
                float v = acc2[mt][nt][r] + bsv;
                acc2[mt][nt][r] = v;
                sq[mt][r] += v * v;
            }
        }
    #pragma unroll
    for (int off = 1; off < 16; off <<= 1)
        #pragma unroll
        for (int mt = 0; mt < 2; mt++)
            #pragma unroll
            for (int r = 0; r < 4; r++)
                sq[mt][r] += __shfl_xor(sq[mt][r], off, 64);
    if (li == 0) {
        #pragma unroll
        for (int mt = 0; mt < 2; mt++)
            #pragma unroll
            for (int r = 0; r < 4; r++)
                redq[(mt * 16 + quad * 4 + r) * 4 + wv] = sq[mt][r];
    }
    __syncthreads();
    #pragma unroll
    for (int mt = 0; mt < 2; mt++)
        #pragma unroll
        for (int r = 0; r < 4; r++) {
            int rowm = mt * 16 + quad * 4 + r;
            float tot = redq[rowm * 4 + 0] + redq[rowm * 4 + 1] +
                        redq[rowm * 4 + 2] + redq[rowm * 4 + 3];
            float inv = 1.f / (sqrtf(tot) + 1e-4f);
            #pragma unroll
            for (int nt = 0; nt < 4; nt++) {
                float v = acc2[mt][nt][r] * inv;
                unsigned short h, l;
                split_hl(v, h, l);
                int col = n0w + nt * 16 + li;
                emh[rowm * 264 + col] = h;
                eml[rowm * 264 + col] = l;
            }
        }
    __syncthreads();

    // ---- phase D: scores = embed @ zn^T (wave covers 128 z's) ----
    f32x4 acc3[2][8];
    #pragma unroll
    for (int i = 0; i < 2; i++)
        #pragma unroll
        for (int j = 0; j < 8; j++) acc3[i][j] = zz;
    int zn0 = wv * 128;
    #pragma unroll
    for (int ks = 0; ks < 8; ks++) {
        int ko = ks * 32 + quad * 8;
        bf16x8 ah0 = *(const bf16x8*)&emh[li * 264 + ko];
        bf16x8 al0 = *(const bf16x8*)&eml[li * 264 + ko];
        bf16x8 ah1 = *(const bf16x8*)&emh[(16 + li) * 264 + ko];
        bf16x8 al1 = *(const bf16x8*)&eml[(16 + li) * 264 + ko];
        #pragma unroll
        for (int nt = 0; nt < 8; nt++) {
            size_t zo = (size_t)(zn0 + nt * 16 + li) * EDIM + ko;
            bf16x8 bh = *(const bf16x8*)(znh + zo);
            bf16x8 bl = *(const bf16x8*)(znl + zo);
            acc3[0][nt] = __builtin_amdgcn_mfma_f32_16x16x32_bf16(ah0, bh, acc3[0][nt], 0, 0, 0);
            acc3[0][nt] = __builtin_amdgcn_mfma_f32_16x16x32_bf16(ah0, bl, acc3[0][nt], 0, 0, 0);
            acc3[0][nt] = __builtin_amdgcn_mfma_f32_16x16x32_bf16(al0, bh, acc3[0][nt], 0, 0, 0);
            acc3[1][nt] = __builtin_amdgcn_mfma_f32_16x16x32_bf16(ah1, bh, acc3[1][nt], 0, 0, 0);
            acc3[1][nt] = __builtin_amdgcn_mfma_f32_16x16x32_bf16(ah1, bl, acc3[1][nt], 0, 0, 0);
            acc3[1][nt] = __builtin_amdgcn_mfma_f32_16x16x32_bf16(al1, bh, acc3[1][nt], 0, 0, 0);
        }
    }

    // ---- phase E ----
    if (phi == 0) {
        #pragma unroll
        for (int mt = 0; mt < 2; mt++)
            #pragma unroll
            for (int nt = 0; nt < 8; nt++)
                #pragma unroll
                for (int r = 0; r < 4; r++)
                    Cm[(size_t)(b0 + mt * 16 + quad * 4 + r) * NZV + zn0 + nt * 16 + li] =
                        acc3[mt][nt][r];
    } else {
        #pragma unroll
        for (int mt = 0; mt < 2; mt++)
            #pragma unroll
            for (int r = 0; r < 4; r++) {
                float best = -3.0e38f; int bn = 0;
                #pragma unroll
                for (int nt = 0; nt < 8; nt++) {
                    float v = acc3[mt][nt][r];
                    int n = zn0 + nt * 16 + li;
                    if (v > best) { best = v; bn = n; }
                }
                #pragma unroll
                for (int off = 1; off < 16; off <<= 1) {
                    float ov = __shfl_xor(best, off, 64);
                    int   on = __shfl_xor(bn, off, 64);
                    if (ov > best || (ov == best && on < bn)) { best = ov; bn = on; }
                }
                if (li == 0) {
                    int rowm = mt * 16 + quad * 4 + r;
                    argv[rowm * 4 + wv] = best;
                    argn[rowm * 4 + wv] = bn;
                }
            }
        __syncthreads();
        if (tid < 32) {
            float best = argv[tid * 4]; int bn = argn[tid * 4];
            #pragma unroll
            for (int w = 1; w < 4; w++) {
                float v = argv[tid * 4 + w]; int n = argn[tid * 4 + w];
                if (v > best || (v == best && n < bn)) { best = v; bn = n; }
            }
            idxout[b0 + tid] = bn;
        }
    }
}

// ---- output: out[i][j] = exp(scale) * G0[i][idx[j]] -----------------------
__global__ __launch_bounds__(256) void k_out(const float* __restrict__ C,
                                             const int* __restrict__ idx,
                                             const float* __restrict__ scale,
                                             float* __restrict__ out) {
    __shared__ float g[8][NZV];
    __shared__ int   id[2048];
    int i0 = blockIdx.y * 8;
    int j0 = blockIdx.x * 2048;
    float esc = expf(scale[0]);
    for (int u = threadIdx.x; u < 2048; u += 256) id[u] = idx[j0 + u];
    for (int u = threadIdx.x; u < 8 * NZV; u += 256) {
        int r = u >> 9, c = u & 511;
        g[r][c] = C[(size_t)(i0 + r) * NZV + c];
    }
    __syncthreads();
    int jb = threadIdx.x * 8;
    int myid[8];
    #pragma unroll
    for (int u = 0; u < 8; u++) myid[u] = id[jb + u];
    #pragma unroll
    for (int r = 0; r < 8; r++) {
        float4 o0, o1;
        o0.x = esc * g[r][myid[0]]; o0.y = esc * g[r][myid[1]];
        o0.z = esc * g[r][myid[2]]; o0.w = esc * g[r][myid[3]];
        o1.x = esc * g[r][myid[4]]; o1.y = esc * g[r][myid[5]];
        o1.z = esc * g[r][myid[6]]; o1.w = esc * g[r][myid[7]];
        float4* dst = (float4*)(out + (size_t)(i0 + r) * NB + j0 + jb);
        dst[0] = o0; dst[1] = o1;
    }
}

extern "C" void kernel_launch(void* const* d_in, const int* in_sizes, int n_in,
                              void* d_out, int out_size, void* d_ws, size_t ws_size,
                              hipStream_t stream) {
    const int*   s     = (const int*)d_in[0];
    const int*   sp    = (const int*)d_in[1];
    const float* tab   = (const float*)d_in[2];
    const float* wE    = (const float*)d_in[3];
    const float* bE    = (const float*)d_in[4];
    const float* w1a   = (const float*)d_in[5];
    const float* b1a   = (const float*)d_in[6];
    const float* w2a   = (const float*)d_in[7];
    const float* b2a   = (const float*)d_in[8];
    const float* lwa   = (const float*)d_in[9];
    const float* lba   = (const float*)d_in[10];
    const float* w1b   = (const float*)d_in[11];
    const float* b1b   = (const float*)d_in[12];
    const float* w2b   = (const float*)d_in[13];
    const float* b2b   = (const float*)d_in[14];
    const float* lwb   = (const float*)d_in[15];
    const float* lbb   = (const float*)d_in[16];
    const float* zv    = (const float*)d_in[17];
    const float* scale = (const float*)d_in[18];

    float* out = (float*)d_out;
    float* wsf = (float*)d_ws;

    // d_ws layout (float units), ~20.1 MB total
    float* tn   = wsf;                                        // [0, 448)
    float* Aw   = wsf + 448;                                  // [448, 8512)
    float* beff = wsf + 8512;                                 // [8512, 9312)
    int*   idx  = (int*)(wsf + 9312);                         // [9312, 17504)
    float* T    = wsf + 17504;                                // [17504, 297504)
    float* Cm   = wsf + 297504;                               // 8192*512 -> [.., 4491808)
    unsigned short* wh  = (unsigned short*)(wsf + 4491808);   // 409600 u16
    unsigned short* wl  = (unsigned short*)(wsf + 4696608);
    unsigned short* znh = (unsigned short*)(wsf + 4901408);   // 131072 u16
    unsigned short* znl = (unsigned short*)(wsf + 4966944);   // ends 5032480

    k_norm_embed<<<DICT, 64, 0, stream>>>(tab, tn);
    k_prep_zw<<<NZV + 1600, 256, 0, stream>>>(zv, lwa, lwb, znh, znl, wh, wl);
    k_prep_ab<<<34, 256, 0, stream>>>(wE, tn, w1a, b1a, w1b, b1b, bE, Aw, beff);
    k_build_T<<<dim3(25 * DICT, 2), 256, 0, stream>>>(w1a, w1b, Aw, T);
    k_phi<<<dim3(NB / 32, 2), 256, 0, stream>>>(s, sp, T, beff, w2a, b2a, w2b, b2b,
                                                wh, wl, lba, lbb, znh, znl, Cm, idx);
    k_out<<<dim3(NB / 2048, NB / 8), 256, 0, stream>>>(Cm, idx, scale, out);
}